// Round 1
// baseline (1030.452 us; speedup 1.0000x reference)
//
#include <hip/hip_runtime.h>

#define BB 4
#define NN 256
#define CC 256
#define HH 96
#define WW 128
#define P0 (HH*WW)        // 12288
#define TOTPOS 16320      // 12288 + 3072 + 768 + 192

// -------------------- K1: normalize q rows --------------------
__global__ __launch_bounds__(256) void k_qnorm(const float* __restrict__ q,
                                               float* __restrict__ qn) {
    int wid = blockIdx.x * 4 + (threadIdx.x >> 6);   // (b*N+n)
    int lane = threadIdx.x & 63;
    const float4* src = (const float4*)(q + (size_t)wid * CC);
    float4 v = src[lane];
    float ss = v.x*v.x + v.y*v.y + v.z*v.z + v.w*v.w;
    #pragma unroll
    for (int off = 32; off > 0; off >>= 1) ss += __shfl_xor(ss, off, 64);
    float nrm = sqrtf(ss);
    float inv = 1.0f / fmaxf(nrm, 1e-12f);
    float4 o; o.x = v.x*inv; o.y = v.y*inv; o.z = v.z*inv; o.w = v.w*inv;
    ((float4*)(qn + (size_t)wid * CC))[lane] = o;
}

// -------------------- K2: pool + channel-normalize + transpose --------------------
// out layout: fln[((b*C + c) * TOTPOS) + gp]   (positions contiguous per (b,c))
__global__ __launch_bounds__(256) void k_pool_norm(const float* __restrict__ f,
                                                   float* __restrict__ fln) {
    int b = blockIdx.y;
    int gp = blockIdx.x;          // global position 0..16319
    int lvl, pos;
    if (gp < 12288)      { lvl = 0; pos = gp; }
    else if (gp < 15360) { lvl = 1; pos = gp - 12288; }
    else if (gp < 16128) { lvl = 2; pos = gp - 15360; }
    else                 { lvl = 3; pos = gp - 16128; }
    int k = 1 << lvl;
    int wl = WW >> lvl;
    int py = pos / wl, px = pos - py * wl;
    int c = threadIdx.x;
    int iy0 = py * k, ix0 = px * k;
    float sum = 0.f;
    for (int dy = 0; dy < k; ++dy)
        for (int dx = 0; dx < k; ++dx) {
            int ip = (iy0 + dy) * WW + ix0 + dx;
            sum += f[((size_t)b * P0 + ip) * CC + c];
        }
    float val = sum * (1.0f / (float)(k * k));
    // block reduce sum of squares over 256 channels
    float ss = val * val;
    #pragma unroll
    for (int off = 32; off > 0; off >>= 1) ss += __shfl_xor(ss, off, 64);
    __shared__ float red[4];
    __shared__ float s_inv;
    if ((threadIdx.x & 63) == 0) red[threadIdx.x >> 6] = ss;
    __syncthreads();
    if (threadIdx.x == 0) {
        float t = red[0] + red[1] + red[2] + red[3];
        s_inv = 1.0f / fmaxf(sqrtf(t), 1e-12f);
    }
    __syncthreads();
    fln[((size_t)b * CC + c) * TOTPOS + gp] = val * s_inv;
}

// -------------------- K3: c[b,n,p] = sum_c qn[b,n,c] * fln[b,c,p] --------------------
// grid: x=64 position-blocks (levels packed), y=16 n-groups, z=B
__global__ __launch_bounds__(256) void k_gemm(const float* __restrict__ qn,
                                              const float* __restrict__ fln,
                                              float* __restrict__ cws) {
    __shared__ float qnT[CC * 16];   // [c][j]
    int pb = blockIdx.x;
    int ng = blockIdx.y;
    int b  = blockIdx.z;
    int lvlOff, npos, p0;
    if (pb < 48)      { lvlOff = 0;     npos = 12288; p0 = pb * 256; }
    else if (pb < 60) { lvlOff = 12288; npos = 3072;  p0 = (pb - 48) * 256; }
    else if (pb < 63) { lvlOff = 15360; npos = 768;   p0 = (pb - 60) * 256; }
    else              { lvlOff = 16128; npos = 192;   p0 = 0; }
    int n0 = ng * 16;
    int tid = threadIdx.x;
    for (int i = tid; i < CC * 16; i += 256) {
        int j = i & 15, c = i >> 4;
        qnT[i] = qn[((size_t)(b * NN + n0 + j)) * CC + c];
    }
    __syncthreads();
    int p = p0 + tid;
    if (p < npos) {
        const float* fp = fln + ((size_t)b * CC) * TOTPOS + lvlOff + p;
        float acc[16];
        #pragma unroll
        for (int j = 0; j < 16; ++j) acc[j] = 0.f;
        #pragma unroll 4
        for (int c = 0; c < CC; ++c) {
            float v = fp[(size_t)c * TOTPOS];
            const float4* qr = (const float4*)(qnT + c * 16);
            float qv[16];
            *(float4*)&qv[0]  = qr[0];
            *(float4*)&qv[4]  = qr[1];
            *(float4*)&qv[8]  = qr[2];
            *(float4*)&qv[12] = qr[3];
            #pragma unroll
            for (int j = 0; j < 16; ++j) acc[j] += qv[j] * v;
        }
        float* cp = cws + ((size_t)(b * NN + n0)) * TOTPOS + lvlOff + p;
        #pragma unroll
        for (int j = 0; j < 16; ++j) cp[(size_t)j * TOTPOS] = acc[j];
    }
}

// -------------------- K4: upsample + conv1 + relu + conv2 + residual --------------------
// grid: x=48 tiles (6y x 8x of 16x16), y = B*N images
__global__ __launch_bounds__(256) void k_fuse(const float* __restrict__ cws,
                                              const float* __restrict__ w1,
                                              const float* __restrict__ w2,
                                              float* __restrict__ out) {
    __shared__ float cT[4 * 400];     // [ch][20][20]
    __shared__ float hm[16 * 324];    // [oc][18][18]
    __shared__ float w1T[576];        // [ic][ky][kx][oc]
    __shared__ float w2s[144];        // [ic][ky][kx]
    int img  = blockIdx.y;            // b*N + n
    int tile = blockIdx.x;
    int ty0 = (tile >> 3) * 16;
    int tx0 = (tile & 7) * 16;
    int tid = threadIdx.x;

    if (tid < 144) w2s[tid] = w2[tid];
    for (int i = tid; i < 576; i += 256) {
        int oc = i & 15, r = i >> 4;        // r = (ic*3+ky)*3+kx
        w1T[i] = w1[oc * 36 + r];
    }

    const float* cb = cws + (size_t)img * TOTPOS;
    // stage c tile (4 channels, 20x20 halo) — zero outside image (SAME pad)
    for (int i = tid; i < 1600; i += 256) {
        int ch = i / 400, pix = i - ch * 400;
        int hy = pix / 20, hx = pix - hy * 20;
        int gy = ty0 + hy - 2, gx = tx0 + hx - 2;
        float v = 0.f;
        if (gy >= 0 && gy < HH && gx >= 0 && gx < WW) {
            if (ch == 0) {
                v = cb[gy * WW + gx];
            } else {
                int l = ch;
                int hl = HH >> l, wl = WW >> l;
                int lvlOff = (l == 1) ? 12288 : (l == 2) ? 15360 : 16128;
                float invk = (l == 1) ? 0.5f : (l == 2) ? 0.25f : 0.125f;
                float fy = (gy + 0.5f) * invk - 0.5f;
                float fx = (gx + 0.5f) * invk - 0.5f;
                float y0f = floorf(fy), x0f = floorf(fx);
                float ty = fy - y0f, tx = fx - x0f;
                int y0 = (int)y0f, x0 = (int)x0f;
                int y1 = min(y0 + 1, hl - 1);
                y0 = min(max(y0, 0), hl - 1);
                int x1 = min(x0 + 1, wl - 1);
                x0 = min(max(x0, 0), wl - 1);
                const float* base = cb + lvlOff;
                float v00 = base[y0 * wl + x0], v01 = base[y0 * wl + x1];
                float v10 = base[y1 * wl + x0], v11 = base[y1 * wl + x1];
                v = (1.f - ty) * ((1.f - tx) * v00 + tx * v01)
                  +        ty  * ((1.f - tx) * v10 + tx * v11);
            }
        }
        cT[ch * 400 + pix] = v;
    }
    __syncthreads();

    // conv1 + relu into hm; hmid is ZERO outside image (conv2 SAME pads hmid)
    for (int it = 0; it < 2; ++it) {
        int pix = tid + it * 256;
        if (pix < 324) {
            int hy = pix / 18, hx = pix - hy * 18;
            int gy = ty0 + hy - 1, gx = tx0 + hx - 1;
            float acc[16];
            #pragma unroll
            for (int oc = 0; oc < 16; ++oc) acc[oc] = 0.f;
            if (gy >= 0 && gy < HH && gx >= 0 && gx < WW) {
                #pragma unroll
                for (int ic = 0; ic < 4; ++ic)
                    #pragma unroll
                    for (int ky = 0; ky < 3; ++ky)
                        #pragma unroll
                        for (int kx = 0; kx < 3; ++kx) {
                            float cv = cT[ic * 400 + (hy + ky) * 20 + (hx + kx)];
                            const float4* wr = (const float4*)(w1T + ((ic * 3 + ky) * 3 + kx) * 16);
                            float wv[16];
                            *(float4*)&wv[0]  = wr[0];
                            *(float4*)&wv[4]  = wr[1];
                            *(float4*)&wv[8]  = wr[2];
                            *(float4*)&wv[12] = wr[3];
                            #pragma unroll
                            for (int oc = 0; oc < 16; ++oc) acc[oc] += wv[oc] * cv;
                        }
            }
            #pragma unroll
            for (int oc = 0; oc < 16; ++oc)
                hm[oc * 324 + pix] = fmaxf(acc[oc], 0.f);
        }
    }
    __syncthreads();

    // conv2 + residual, one thread per output pixel
    int oy = tid >> 4, ox = tid & 15;
    float sum = 0.f;
    #pragma unroll
    for (int ic = 0; ic < 16; ++ic)
        #pragma unroll
        for (int ky = 0; ky < 3; ++ky)
            #pragma unroll
            for (int kx = 0; kx < 3; ++kx)
                sum += w2s[ic * 9 + ky * 3 + kx] * hm[ic * 324 + (oy + ky) * 18 + (ox + kx)];
    sum += cT[(oy + 2) * 20 + (ox + 2)];
    out[(size_t)img * P0 + (ty0 + oy) * WW + (tx0 + ox)] = sum;
}

extern "C" void kernel_launch(void* const* d_in, const int* in_sizes, int n_in,
                              void* d_out, int out_size, void* d_ws, size_t ws_size,
                              hipStream_t stream) {
    const float* q  = (const float*)d_in[0];
    const float* f  = (const float*)d_in[1];
    const float* w1 = (const float*)d_in[2];
    const float* w2 = (const float*)d_in[3];
    float* out = (float*)d_out;

    float* wsf = (float*)d_ws;
    float* qn  = wsf;                                  // B*N*C          = 262144
    float* fln = qn + (size_t)BB * NN * CC;            // B*C*TOTPOS     = 16711680
    float* cws = fln + (size_t)BB * CC * TOTPOS;       // B*N*TOTPOS     = 16711680

    hipLaunchKernelGGL(k_qnorm, dim3(BB * NN / 4), dim3(256), 0, stream, q, qn);
    hipLaunchKernelGGL(k_pool_norm, dim3(TOTPOS, BB), dim3(256), 0, stream, f, fln);
    hipLaunchKernelGGL(k_gemm, dim3(64, 16, BB), dim3(256), 0, stream, qn, fln, cws);
    hipLaunchKernelGGL(k_fuse, dim3(48, BB * NN), dim3(256), 0, stream, cws, w1, w2, out);
}

// Round 2
// 912.389 us; speedup vs baseline: 1.1294x; 1.1294x over previous
//
#include <hip/hip_runtime.h>
#include <hip/hip_fp16.h>

#define BB 4
#define NN 256
#define CC 256
#define HH 96
#define WW 128
#define P0 (HH*WW)        // 12288
#define TOTPOS 16320      // 12288 + 3072 + 768 + 192

// -------------------- K1: normalize q rows --------------------
__global__ __launch_bounds__(256) void k_qnorm(const float* __restrict__ q,
                                               float* __restrict__ qn) {
    int wid = blockIdx.x * 4 + (threadIdx.x >> 6);   // (b*N+n)
    int lane = threadIdx.x & 63;
    const float4* src = (const float4*)(q + (size_t)wid * CC);
    float4 v = src[lane];
    float ss = v.x*v.x + v.y*v.y + v.z*v.z + v.w*v.w;
    #pragma unroll
    for (int off = 32; off > 0; off >>= 1) ss += __shfl_xor(ss, off, 64);
    float nrm = sqrtf(ss);
    float inv = 1.0f / fmaxf(nrm, 1e-12f);
    float4 o; o.x = v.x*inv; o.y = v.y*inv; o.z = v.z*inv; o.w = v.w*inv;
    ((float4*)(qn + (size_t)wid * CC))[lane] = o;
}

// -------------------- K2: pool + channel-normalize + transpose --------------------
__global__ __launch_bounds__(256) void k_pool_norm(const float* __restrict__ f,
                                                   float* __restrict__ fln) {
    int b = blockIdx.y;
    int gp = blockIdx.x;          // global position 0..16319
    int lvl, pos;
    if (gp < 12288)      { lvl = 0; pos = gp; }
    else if (gp < 15360) { lvl = 1; pos = gp - 12288; }
    else if (gp < 16128) { lvl = 2; pos = gp - 15360; }
    else                 { lvl = 3; pos = gp - 16128; }
    int k = 1 << lvl;
    int wl = WW >> lvl;
    int py = pos / wl, px = pos - py * wl;
    int c = threadIdx.x;
    int iy0 = py * k, ix0 = px * k;
    float sum = 0.f;
    for (int dy = 0; dy < k; ++dy)
        for (int dx = 0; dx < k; ++dx) {
            int ip = (iy0 + dy) * WW + ix0 + dx;
            sum += f[((size_t)b * P0 + ip) * CC + c];
        }
    float val = sum * (1.0f / (float)(k * k));
    float ss = val * val;
    #pragma unroll
    for (int off = 32; off > 0; off >>= 1) ss += __shfl_xor(ss, off, 64);
    __shared__ float red[4];
    __shared__ float s_inv;
    if ((threadIdx.x & 63) == 0) red[threadIdx.x >> 6] = ss;
    __syncthreads();
    if (threadIdx.x == 0) {
        float t = red[0] + red[1] + red[2] + red[3];
        s_inv = 1.0f / fmaxf(sqrtf(t), 1e-12f);
    }
    __syncthreads();
    fln[((size_t)b * CC + c) * TOTPOS + gp] = val * s_inv;
}

// -------------------- K3: c[b,n,p] = sum_c qn[b,n,c] * fln[b,c,p] --------------------
__global__ __launch_bounds__(256) void k_gemm(const float* __restrict__ qn,
                                              const float* __restrict__ fln,
                                              float* __restrict__ cws) {
    __shared__ float qnT[CC * 16];   // [c][j]
    int pb = blockIdx.x;
    int ng = blockIdx.y;
    int b  = blockIdx.z;
    int lvlOff, npos, p0;
    if (pb < 48)      { lvlOff = 0;     npos = 12288; p0 = pb * 256; }
    else if (pb < 60) { lvlOff = 12288; npos = 3072;  p0 = (pb - 48) * 256; }
    else if (pb < 63) { lvlOff = 15360; npos = 768;   p0 = (pb - 60) * 256; }
    else              { lvlOff = 16128; npos = 192;   p0 = 0; }
    int n0 = ng * 16;
    int tid = threadIdx.x;
    for (int i = tid; i < CC * 16; i += 256) {
        int j = i & 15, c = i >> 4;
        qnT[i] = qn[((size_t)(b * NN + n0 + j)) * CC + c];
    }
    __syncthreads();
    int p = p0 + tid;
    if (p < npos) {
        const float* fp = fln + ((size_t)b * CC) * TOTPOS + lvlOff + p;
        float acc[16];
        #pragma unroll
        for (int j = 0; j < 16; ++j) acc[j] = 0.f;
        #pragma unroll 4
        for (int c = 0; c < CC; ++c) {
            float v = fp[(size_t)c * TOTPOS];
            const float4* qr = (const float4*)(qnT + c * 16);
            float qv[16];
            *(float4*)&qv[0]  = qr[0];
            *(float4*)&qv[4]  = qr[1];
            *(float4*)&qv[8]  = qr[2];
            *(float4*)&qv[12] = qr[3];
            #pragma unroll
            for (int j = 0; j < 16; ++j) acc[j] += qv[j] * v;
        }
        float* cp = cws + ((size_t)(b * NN + n0)) * TOTPOS + lvlOff + p;
        #pragma unroll
        for (int j = 0; j < 16; ++j) cp[(size_t)j * TOTPOS] = acc[j];
    }
}

// -------------------- K4: upsample + conv1 + relu + conv2 + residual --------------------
// 32x32 output tile per block; grid x = 12 tiles (3x4), y = B*N images.
// conv1: register-tiled 2x4 patch x 16 oc per thread; weights via uniform
// (scalar) loads straight from global; hmid staged in LDS as f16.
__global__ __launch_bounds__(256, 2) void k_fuse(const float* __restrict__ cws,
                                                 const float* __restrict__ w1,
                                                 const float* __restrict__ w2,
                                                 float* __restrict__ out) {
    __shared__ float  cT[4 * 36 * 38];          // [ch][ry 0..35][rx 0..37], rx>=36 pad=0
    __shared__ __half hm[16 * 34 * 38];         // [oc][hrow 0..33][hcol 0..37(34..37 pad)]
    int img  = blockIdx.y;            // b*N + n
    int tile = blockIdx.x;
    int ty0 = (tile >> 2) * 32;
    int tx0 = (tile & 3) * 32;
    int tid = threadIdx.x;
    const float* cb = cws + (size_t)img * TOTPOS;

    // ---- stage cT: region rows/cols -2..33 rel to tile (idx +2), SAME-pad zeros ----
    for (int i = tid; i < 4 * 36 * 38; i += 256) {
        int ch = i / 1368, rem = i - ch * 1368;
        int ry = rem / 38, rx = rem - ry * 38;
        float v = 0.f;
        if (rx < 36) {
            int gy = ty0 + ry - 2, gx = tx0 + rx - 2;
            if ((unsigned)gy < HH && (unsigned)gx < WW) {
                if (ch == 0) {
                    v = cb[gy * WW + gx];
                } else {
                    int l = ch;
                    int hl = HH >> l, wl = WW >> l;
                    int lvlOff = (l == 1) ? 12288 : (l == 2) ? 15360 : 16128;
                    float invk = (l == 1) ? 0.5f : (l == 2) ? 0.25f : 0.125f;
                    float fy = (gy + 0.5f) * invk - 0.5f;
                    float fx = (gx + 0.5f) * invk - 0.5f;
                    float y0f = floorf(fy), x0f = floorf(fx);
                    float ty = fy - y0f, tx = fx - x0f;
                    int y0 = (int)y0f, x0 = (int)x0f;
                    int y1 = min(y0 + 1, hl - 1);
                    y0 = min(max(y0, 0), hl - 1);
                    int x1 = min(x0 + 1, wl - 1);
                    x0 = min(max(x0, 0), wl - 1);
                    const float* base = cb + lvlOff;
                    float v00 = base[y0 * wl + x0], v01 = base[y0 * wl + x1];
                    float v10 = base[y1 * wl + x0], v11 = base[y1 * wl + x1];
                    v = (1.f - ty) * ((1.f - tx) * v00 + tx * v01)
                      +        ty  * ((1.f - tx) * v10 + tx * v11);
                }
            }
        }
        cT[i] = v;
    }
    __syncthreads();

    // ---- conv1 + relu -> hm (f16). hmid region hrow 0..33 (=out rows -1..32),
    // cols 0..33 needed (34..35 garbage). 153 tasks of 2x4 px x 16 oc. ----
    if (tid < 153) {
        int prow = tid / 9, pcol = tid - prow * 9;
        int r0 = prow * 2, c0 = pcol * 4;
        float acc[2][4][16];
        #pragma unroll
        for (int rr = 0; rr < 2; ++rr)
            #pragma unroll
            for (int q = 0; q < 4; ++q)
                #pragma unroll
                for (int oc = 0; oc < 16; ++oc) acc[rr][q][oc] = 0.f;
        for (int ic = 0; ic < 4; ++ic) {   // dynamic: keep I-cache small
            float win[4][6];
            #pragma unroll
            for (int r = 0; r < 4; ++r)
                #pragma unroll
                for (int q = 0; q < 6; ++q)
                    win[r][q] = cT[ic * 1368 + (r0 + r) * 38 + c0 + q];
            const float* wic = w1 + ic * 9;   // uniform -> s_load
            #pragma unroll
            for (int ky = 0; ky < 3; ++ky)
                #pragma unroll
                for (int kx = 0; kx < 3; ++kx) {
                    #pragma unroll
                    for (int oc = 0; oc < 16; ++oc) {
                        float w = wic[oc * 36 + ky * 3 + kx];
                        #pragma unroll
                        for (int rr = 0; rr < 2; ++rr)
                            #pragma unroll
                            for (int q = 0; q < 4; ++q)
                                acc[rr][q][oc] = fmaf(w, win[rr + ky][q + kx], acc[rr][q][oc]);
                    }
                }
        }
        #pragma unroll
        for (int oc = 0; oc < 16; ++oc)
            #pragma unroll
            for (int rr = 0; rr < 2; ++rr) {
                int hrow = r0 + rr;
                int iy = ty0 + hrow - 1;
                bool vy = (unsigned)iy < HH;
                #pragma unroll
                for (int qq = 0; qq < 2; ++qq) {
                    int hc = c0 + qq * 2;
                    int ix0 = tx0 + hc - 1;
                    float a0 = (vy && (unsigned)ix0 < WW) ? fmaxf(acc[rr][qq*2][oc], 0.f) : 0.f;
                    float a1 = (vy && (unsigned)(ix0+1) < WW) ? fmaxf(acc[rr][qq*2+1][oc], 0.f) : 0.f;
                    *(__half2*)&hm[oc * (34*38) + hrow * 38 + hc] = __floats2half2_rn(a0, a1);
                }
            }
    }
    __syncthreads();

    // ---- conv2 + residual: each thread 1x4 output px ----
    int oy = tid >> 3, ox4 = (tid & 7) * 4;
    float a2[4] = {0.f, 0.f, 0.f, 0.f};
    for (int ic = 0; ic < 16; ++ic) {       // dynamic
        float h[3][6];
        #pragma unroll
        for (int r = 0; r < 3; ++r)
            #pragma unroll
            for (int p = 0; p < 3; ++p) {
                __half2 t = *(const __half2*)&hm[ic * (34*38) + (oy + r) * 38 + ox4 + p * 2];
                float2 f2 = __half22float2(t);
                h[r][p*2] = f2.x; h[r][p*2+1] = f2.y;
            }
        const float* wic = w2 + ic * 9;     // uniform -> s_load
        #pragma unroll
        for (int ky = 0; ky < 3; ++ky)
            #pragma unroll
            for (int kx = 0; kx < 3; ++kx) {
                float w = wic[ky * 3 + kx];
                #pragma unroll
                for (int q = 0; q < 4; ++q)
                    a2[q] = fmaf(w, h[ky][q + kx], a2[q]);
            }
    }
    float4 o;
    o.x = a2[0] + cT[(oy + 2) * 38 + ox4 + 2];
    o.y = a2[1] + cT[(oy + 2) * 38 + ox4 + 3];
    o.z = a2[2] + cT[(oy + 2) * 38 + ox4 + 4];
    o.w = a2[3] + cT[(oy + 2) * 38 + ox4 + 5];
    *(float4*)&out[(size_t)img * P0 + (ty0 + oy) * WW + tx0 + ox4] = o;
}

extern "C" void kernel_launch(void* const* d_in, const int* in_sizes, int n_in,
                              void* d_out, int out_size, void* d_ws, size_t ws_size,
                              hipStream_t stream) {
    const float* q  = (const float*)d_in[0];
    const float* f  = (const float*)d_in[1];
    const float* w1 = (const float*)d_in[2];
    const float* w2 = (const float*)d_in[3];
    float* out = (float*)d_out;

    float* wsf = (float*)d_ws;
    float* qn  = wsf;                                  // B*N*C
    float* fln = qn + (size_t)BB * NN * CC;            // B*C*TOTPOS
    float* cws = fln + (size_t)BB * CC * TOTPOS;       // B*N*TOTPOS

    hipLaunchKernelGGL(k_qnorm, dim3(BB * NN / 4), dim3(256), 0, stream, q, qn);
    hipLaunchKernelGGL(k_pool_norm, dim3(TOTPOS, BB), dim3(256), 0, stream, f, fln);
    hipLaunchKernelGGL(k_gemm, dim3(64, 16, BB), dim3(256), 0, stream, qn, fln, cws);
    hipLaunchKernelGGL(k_fuse, dim3(12, BB * NN), dim3(256), 0, stream, cws, w1, w2, out);
}

// Round 4
// 709.047 us; speedup vs baseline: 1.4533x; 1.2868x over previous
//
#include <hip/hip_runtime.h>
#include <hip/hip_fp16.h>

#define BB 4
#define NN 256
#define CC 256
#define HH 96
#define WW 128
#define P0 (HH*WW)        // 12288
#define TOTPOS 16320      // 12288 + 3072 + 768 + 192

typedef _Float16 f16x4 __attribute__((ext_vector_type(4)));
typedef _Float16 f16x8 __attribute__((ext_vector_type(8)));
typedef _Float16 h2    __attribute__((ext_vector_type(2)));
typedef float    f32x4 __attribute__((ext_vector_type(4)));

#if defined(__has_builtin)
#if __has_builtin(__builtin_amdgcn_fdot2)
#define FDOT2(a,b,c) __builtin_amdgcn_fdot2((a),(b),(c),false)
#endif
#endif
#ifndef FDOT2
#define FDOT2(a,b,c) ((c) + (float)(a)[0]*(float)(b)[0] + (float)(a)[1]*(float)(b)[1])
#endif

// -------------------- K1: normalize q rows --------------------
__global__ __launch_bounds__(256) void k_qnorm(const float* __restrict__ q,
                                               float* __restrict__ qn) {
    int wid = blockIdx.x * 4 + (threadIdx.x >> 6);   // (b*N+n)
    int lane = threadIdx.x & 63;
    const float4* src = (const float4*)(q + (size_t)wid * CC);
    float4 v = src[lane];
    float ss = v.x*v.x + v.y*v.y + v.z*v.z + v.w*v.w;
    #pragma unroll
    for (int off = 32; off > 0; off >>= 1) ss += __shfl_xor(ss, off, 64);
    float nrm = sqrtf(ss);
    float inv = 1.0f / fmaxf(nrm, 1e-12f);
    float4 o; o.x = v.x*inv; o.y = v.y*inv; o.z = v.z*inv; o.w = v.w*inv;
    ((float4*)(qn + (size_t)wid * CC))[lane] = o;
}

// -------------------- K2: pool + channel-normalize + transpose --------------------
__global__ __launch_bounds__(256) void k_pool_norm(const float* __restrict__ f,
                                                   float* __restrict__ fln) {
    int b = blockIdx.y;
    int gp = blockIdx.x;          // global position 0..16319
    int lvl, pos;
    if (gp < 12288)      { lvl = 0; pos = gp; }
    else if (gp < 15360) { lvl = 1; pos = gp - 12288; }
    else if (gp < 16128) { lvl = 2; pos = gp - 15360; }
    else                 { lvl = 3; pos = gp - 16128; }
    int k = 1 << lvl;
    int wl = WW >> lvl;
    int py = pos / wl, px = pos - py * wl;
    int c = threadIdx.x;
    int iy0 = py * k, ix0 = px * k;
    float sum = 0.f;
    for (int dy = 0; dy < k; ++dy)
        for (int dx = 0; dx < k; ++dx) {
            int ip = (iy0 + dy) * WW + ix0 + dx;
            sum += f[((size_t)b * P0 + ip) * CC + c];
        }
    float val = sum * (1.0f / (float)(k * k));
    float ss = val * val;
    #pragma unroll
    for (int off = 32; off > 0; off >>= 1) ss += __shfl_xor(ss, off, 64);
    __shared__ float red[4];
    __shared__ float s_inv;
    if ((threadIdx.x & 63) == 0) red[threadIdx.x >> 6] = ss;
    __syncthreads();
    if (threadIdx.x == 0) {
        float t = red[0] + red[1] + red[2] + red[3];
        s_inv = 1.0f / fmaxf(sqrtf(t), 1e-12f);
    }
    __syncthreads();
    fln[((size_t)b * CC + c) * TOTPOS + gp] = val * s_inv;
}

// -------------------- K3: c[b,n,p] = sum_c qn[b,n,c] * fln[b,c,p] --------------------
__global__ __launch_bounds__(256) void k_gemm(const float* __restrict__ qn,
                                              const float* __restrict__ fln,
                                              float* __restrict__ cws) {
    __shared__ float qnT[CC * 16];   // [c][j]
    int pb = blockIdx.x;
    int ng = blockIdx.y;
    int b  = blockIdx.z;
    int lvlOff, npos, p0;
    if (pb < 48)      { lvlOff = 0;     npos = 12288; p0 = pb * 256; }
    else if (pb < 60) { lvlOff = 12288; npos = 3072;  p0 = (pb - 48) * 256; }
    else if (pb < 63) { lvlOff = 15360; npos = 768;   p0 = (pb - 60) * 256; }
    else              { lvlOff = 16128; npos = 192;   p0 = 0; }
    int n0 = ng * 16;
    int tid = threadIdx.x;
    for (int i = tid; i < CC * 16; i += 256) {
        int j = i & 15, c = i >> 4;
        qnT[i] = qn[((size_t)(b * NN + n0 + j)) * CC + c];
    }
    __syncthreads();
    int p = p0 + tid;
    if (p < npos) {
        const float* fp = fln + ((size_t)b * CC) * TOTPOS + lvlOff + p;
        float acc[16];
        #pragma unroll
        for (int j = 0; j < 16; ++j) acc[j] = 0.f;
        #pragma unroll 4
        for (int c = 0; c < CC; ++c) {
            float v = fp[(size_t)c * TOTPOS];
            const float4* qr = (const float4*)(qnT + c * 16);
            float qv[16];
            *(float4*)&qv[0]  = qr[0];
            *(float4*)&qv[4]  = qr[1];
            *(float4*)&qv[8]  = qr[2];
            *(float4*)&qv[12] = qr[3];
            #pragma unroll
            for (int j = 0; j < 16; ++j) acc[j] += qv[j] * v;
        }
        float* cp = cws + ((size_t)(b * NN + n0)) * TOTPOS + lvlOff + p;
        #pragma unroll
        for (int j = 0; j < 16; ++j) cp[(size_t)j * TOTPOS] = acc[j];
    }
}

// -------------------- K4: upsample + MFMA conv1 + relu + conv2 + residual --------------------
// 8 output rows x 128 cols per block; grid x = 12 strips, y = B*N images.
// cT: f16 channel-interleaved [ry 0..11][rx 0..131][ic 0..3], rows y0-2..y0+9, cols -2..129.
// hm: __half [oc 0..15][hy 0..9][hx 0..131]; hy <-> y_img = y0+hy-1, hx <-> x_img = hx-1.
//     (R1-proven layout/structure for conv2.)
// conv1: one mfma_f32_16x16x32_f16 (K=32 = taps kk 0..7, ic fast) + (2,2)-tap via fdot2.
__global__ __launch_bounds__(256, 2) void k_fuse(const float* __restrict__ cws,
                                                 const float* __restrict__ w1,
                                                 const float* __restrict__ w2,
                                                 float* __restrict__ out) {
    __shared__ _Float16 cT[12 * 132 * 4];      // 12672 B
    __shared__ __half   hm[16 * 10 * 132];     // 42240 B
    __shared__ float    w2s[144];
    int img   = blockIdx.y;
    int strip = blockIdx.x;
    int y0 = strip * 8;
    int tid = threadIdx.x;
    int lane = tid & 63, wv = tid >> 6;
    int oc = lane & 15, og = lane >> 4;        // oc doubles as A-row (pixel-in-16) index
    const float* cb = cws + (size_t)img * TOTPOS;

    if (tid < 144) w2s[tid] = w2[tid];

    // ---- B fragment: slot (og,e) holds k = og*8+e; k = kk*4+ic (kk=tap 0..7, ic=k&3) ----
    f16x8 bf;
    #pragma unroll
    for (int e = 0; e < 8; ++e) {
        int k = og * 8 + e;
        bf[e] = (_Float16)w1[oc * 36 + (k & 3) * 9 + (k >> 2)];
    }
    // ---- (ky=2,kx=2) tap weights for this oc, ic pairs (0,1) and (2,3) ----
    h2 w22a, w22b;
    w22a[0] = (_Float16)w1[oc * 36 + 0 * 9 + 8];
    w22a[1] = (_Float16)w1[oc * 36 + 1 * 9 + 8];
    w22b[0] = (_Float16)w1[oc * 36 + 2 * 9 + 8];
    w22b[1] = (_Float16)w1[oc * 36 + 3 * 9 + 8];
    // ---- A-fragment LDS offsets (f16 units): e<4 -> kk=2og, e>=4 -> kk=2og+1 ----
    int ofs0, ofs1;
    {
        int kk0 = 2 * og,     ky0 = kk0 / 3, kx0 = kk0 - ky0 * 3;
        int kk1 = 2 * og + 1, ky1 = kk1 / 3, kx1 = kk1 - ky1 * 3;
        ofs0 = (ky0 * 132 + kx0 + 1 + oc) * 4;
        ofs1 = (ky1 * 132 + kx1 + 1 + oc) * 4;
    }

    // ---- zero hm ----
    {
        uint4 z; z.x = z.y = z.z = z.w = 0u;
        uint4* hp = (uint4*)hm;
        for (int i = tid; i < (16 * 10 * 132 * 2) / 16; i += 256) hp[i] = z;
    }
    // ---- stage cT: level0 copy + bilinear upsample levels 1-3, SAME-pad zeros ----
    for (int i = tid; i < 12 * 132; i += 256) {
        int ry = i / 132, rx = i - ry * 132;
        int gy = y0 + ry - 2, gx = rx - 2;
        f16x4 vv = {(_Float16)0.f, (_Float16)0.f, (_Float16)0.f, (_Float16)0.f};
        if ((unsigned)gy < HH && (unsigned)gx < WW) {
            vv[0] = (_Float16)cb[gy * WW + gx];
            #pragma unroll
            for (int l = 1; l < 4; ++l) {
                int hl = HH >> l, wl = WW >> l;
                int lvlOff = (l == 1) ? 12288 : (l == 2) ? 15360 : 16128;
                float invk = (l == 1) ? 0.5f : (l == 2) ? 0.25f : 0.125f;
                float fy = (gy + 0.5f) * invk - 0.5f;
                float fx = (gx + 0.5f) * invk - 0.5f;
                float y0f = floorf(fy), x0f = floorf(fx);
                float ty = fy - y0f, tx = fx - x0f;
                int iy = (int)y0f, ix = (int)x0f;
                int y1 = min(iy + 1, hl - 1);
                iy = min(max(iy, 0), hl - 1);
                int x1 = min(ix + 1, wl - 1);
                ix = min(max(ix, 0), wl - 1);
                const float* base = cb + lvlOff;
                float v00 = base[iy * wl + ix], v01 = base[iy * wl + x1];
                float v10 = base[y1 * wl + ix], v11 = base[y1 * wl + x1];
                float v = (1.f - ty) * ((1.f - tx) * v00 + tx * v01)
                        +        ty  * ((1.f - tx) * v10 + tx * v11);
                vv[l] = (_Float16)v;
            }
        }
        *(f16x4*)&cT[i * 4] = vv;
    }
    __syncthreads();

    // ---- conv1: 80 M-tiles (hy 0..9, xg 0..7), 20 per wave ----
    for (int t = wv * 20; t < wv * 20 + 20; ++t) {
        int hy = t >> 3, xg = t & 7;
        if ((unsigned)(y0 + hy - 1) >= (unsigned)HH) continue;   // row outside: stays 0
        int base = hy * 528 + xg * 64;
        f16x4 a0 = *(const f16x4*)&cT[base + ofs0];
        f16x4 a1 = *(const f16x4*)&cT[base + ofs1];
        f16x8 A;
        #pragma unroll
        for (int e = 0; e < 4; ++e) { A[e] = a0[e]; A[4 + e] = a1[e]; }
        f32x4 acc = {0.f, 0.f, 0.f, 0.f};
        acc = __builtin_amdgcn_mfma_f32_16x16x32_f16(A, bf, acc, 0, 0, 0);
        int xb = xg * 16 + og * 4;            // pixel x for r=0 (D row = og*4+r)
        #pragma unroll
        for (int r = 0; r < 4; ++r) {
            int x = xb + r;
            f16x4 cv = *(const f16x4*)&cT[(hy + 2) * 528 + (x + 3) * 4];  // tap (2,2), broadcast
            h2 lo, hi;
            lo[0] = cv[0]; lo[1] = cv[1];
            hi[0] = cv[2]; hi[1] = cv[3];
            float v = acc[r];
            v = FDOT2(lo, w22a, v);
            v = FDOT2(hi, w22b, v);
            hm[oc * 1320 + hy * 132 + (x + 1)] = __float2half(fmaxf(v, 0.f));
        }
    }
    __syncthreads();

    // ---- conv2 + residual (R1-proven structure): each thread 1x4 output px ----
    int oy = tid >> 5, x4 = (tid & 31) * 4;
    float a2[4] = {0.f, 0.f, 0.f, 0.f};
    for (int ic = 0; ic < 16; ++ic) {
        float h[3][6];
        #pragma unroll
        for (int r = 0; r < 3; ++r)
            #pragma unroll
            for (int p = 0; p < 3; ++p) {
                __half2 t = *(const __half2*)&hm[ic * 1320 + (oy + r) * 132 + x4 + p * 2];
                float2 f2 = __half22float2(t);
                h[r][p*2] = f2.x; h[r][p*2+1] = f2.y;
            }
        #pragma unroll
        for (int ky = 0; ky < 3; ++ky)
            #pragma unroll
            for (int kx = 0; kx < 3; ++kx) {
                float w = w2s[ic * 9 + ky * 3 + kx];
                #pragma unroll
                for (int q = 0; q < 4; ++q)
                    a2[q] = fmaf(w, h[ky][q + kx], a2[q]);
            }
    }
    int gy = y0 + oy;
    const float4 res = *(const float4*)&cb[gy * WW + x4];
    float4 o;
    o.x = a2[0] + res.x; o.y = a2[1] + res.y;
    o.z = a2[2] + res.z; o.w = a2[3] + res.w;
    *(float4*)&out[(size_t)img * P0 + gy * WW + x4] = o;
}

extern "C" void kernel_launch(void* const* d_in, const int* in_sizes, int n_in,
                              void* d_out, int out_size, void* d_ws, size_t ws_size,
                              hipStream_t stream) {
    const float* q  = (const float*)d_in[0];
    const float* f  = (const float*)d_in[1];
    const float* w1 = (const float*)d_in[2];
    const float* w2 = (const float*)d_in[3];
    float* out = (float*)d_out;

    float* wsf = (float*)d_ws;
    float* qn  = wsf;                                  // B*N*C
    float* fln = qn + (size_t)BB * NN * CC;            // B*C*TOTPOS
    float* cws = fln + (size_t)BB * CC * TOTPOS;       // B*N*TOTPOS

    hipLaunchKernelGGL(k_qnorm, dim3(BB * NN / 4), dim3(256), 0, stream, q, qn);
    hipLaunchKernelGGL(k_pool_norm, dim3(TOTPOS, BB), dim3(256), 0, stream, f, fln);
    hipLaunchKernelGGL(k_gemm, dim3(64, 16, BB), dim3(256), 0, stream, qn, fln, cws);
    hipLaunchKernelGGL(k_fuse, dim3(12, BB * NN), dim3(256), 0, stream, cws, w1, w2, out);
}

// Round 5
// 480.305 us; speedup vs baseline: 2.1454x; 1.4762x over previous
//
#include <hip/hip_runtime.h>
#include <hip/hip_fp16.h>

#define BB 4
#define NN 256
#define CC 256
#define HH 96
#define WW 128
#define P0 (HH*WW)        // 12288
#define TOTPOS 16320      // 12288 + 3072 + 768 + 192 = 255*64 = 510*32

typedef _Float16 f16x4 __attribute__((ext_vector_type(4)));
typedef _Float16 f16x8 __attribute__((ext_vector_type(8)));
typedef _Float16 h2    __attribute__((ext_vector_type(2)));
typedef float    f32x4 __attribute__((ext_vector_type(4)));

#if defined(__has_builtin)
#if __has_builtin(__builtin_amdgcn_fdot2)
#define FDOT2(a,b,c) __builtin_amdgcn_fdot2((a),(b),(c),false)
#endif
#endif
#ifndef FDOT2
#define FDOT2(a,b,c) ((c) + (float)(a)[0]*(float)(b)[0] + (float)(a)[1]*(float)(b)[1])
#endif

// -------------------- K1: normalize q rows -> f16 --------------------
__global__ __launch_bounds__(256) void k_qnorm(const float* __restrict__ q,
                                               _Float16* __restrict__ qn16) {
    int wid = blockIdx.x * 4 + (threadIdx.x >> 6);   // (b*N+n)
    int lane = threadIdx.x & 63;
    const float4* src = (const float4*)(q + (size_t)wid * CC);
    float4 v = src[lane];
    float ss = v.x*v.x + v.y*v.y + v.z*v.z + v.w*v.w;
    #pragma unroll
    for (int off = 32; off > 0; off >>= 1) ss += __shfl_xor(ss, off, 64);
    float inv = 1.0f / fmaxf(sqrtf(ss), 1e-12f);
    f16x4 o;
    o[0] = (_Float16)(v.x*inv); o[1] = (_Float16)(v.y*inv);
    o[2] = (_Float16)(v.z*inv); o[3] = (_Float16)(v.w*inv);
    *(f16x4*)(qn16 + (size_t)wid * CC + lane * 4) = o;
}

// -------------------- K2: pool + channel-normalize -> f16 [b][p][c] --------------------
__global__ __launch_bounds__(256) void k_pool_norm(const float* __restrict__ f,
                                                   _Float16* __restrict__ flnT) {
    int b = blockIdx.y;
    int gp = blockIdx.x;          // global position 0..16319
    int lvl, pos;
    if (gp < 12288)      { lvl = 0; pos = gp; }
    else if (gp < 15360) { lvl = 1; pos = gp - 12288; }
    else if (gp < 16128) { lvl = 2; pos = gp - 15360; }
    else                 { lvl = 3; pos = gp - 16128; }
    int k = 1 << lvl;
    int wl = WW >> lvl;
    int py = pos / wl, px = pos - py * wl;
    int c = threadIdx.x;
    int iy0 = py * k, ix0 = px * k;
    float sum = 0.f;
    for (int dy = 0; dy < k; ++dy)
        for (int dx = 0; dx < k; ++dx) {
            int ip = (iy0 + dy) * WW + ix0 + dx;
            sum += f[((size_t)b * P0 + ip) * CC + c];
        }
    float val = sum * (1.0f / (float)(k * k));
    float ss = val * val;
    #pragma unroll
    for (int off = 32; off > 0; off >>= 1) ss += __shfl_xor(ss, off, 64);
    __shared__ float red[4];
    __shared__ float s_inv;
    if ((threadIdx.x & 63) == 0) red[threadIdx.x >> 6] = ss;
    __syncthreads();
    if (threadIdx.x == 0) {
        float t = red[0] + red[1] + red[2] + red[3];
        s_inv = 1.0f / fmaxf(sqrtf(t), 1e-12f);
    }
    __syncthreads();
    flnT[((size_t)b * TOTPOS + gp) * CC + c] = (_Float16)(val * s_inv);   // coalesced
}

// -------------------- K3: MFMA GEMM  c[b,n,p] = sum_c qn[n,c]*fln[p,c] --------------------
// No LDS. Per wave: 32x32 output tile, A/B fragments loaded straight from global
// (16B per lane; qn16 L2-resident, flnT reused 4x via L2).
// Fragment convention (HW-verified in R3): A row=lane&15, k=(lane>>4)*8+e;
// B col=lane&15, same k map; D col=lane&15, row=(lane>>4)*4+r.
__global__ __launch_bounds__(256, 4) void k_gemm(const _Float16* __restrict__ qn16,
                                                 const _Float16* __restrict__ flnT,
                                                 float* __restrict__ cws) {
    int b = blockIdx.z;
    int wv = threadIdx.x >> 6, lane = threadIdx.x & 63;
    int m0 = blockIdx.y * 64 + (wv >> 1) * 32;       // n-origin of wave tile
    int p0 = blockIdx.x * 64 + (wv & 1) * 32;        // p-origin of wave tile
    int r = lane & 15, og = lane >> 4;

    const f16x8* A0p = (const f16x8*)(qn16 + ((size_t)(b * NN + m0 + r)) * CC) + og;
    const f16x8* A1p = (const f16x8*)(qn16 + ((size_t)(b * NN + m0 + 16 + r)) * CC) + og;
    const f16x8* B0p = (const f16x8*)(flnT + ((size_t)b * TOTPOS + p0 + r) * CC) + og;
    const f16x8* B1p = (const f16x8*)(flnT + ((size_t)b * TOTPOS + p0 + 16 + r) * CC) + og;

    f32x4 acc00 = {0,0,0,0}, acc01 = {0,0,0,0}, acc10 = {0,0,0,0}, acc11 = {0,0,0,0};
    #pragma unroll 4
    for (int ko = 0; ko < 8; ++ko) {
        f16x8 a0 = A0p[ko * 4];
        f16x8 a1 = A1p[ko * 4];
        f16x8 b0 = B0p[ko * 4];
        f16x8 b1 = B1p[ko * 4];
        acc00 = __builtin_amdgcn_mfma_f32_16x16x32_f16(a0, b0, acc00, 0, 0, 0);
        acc01 = __builtin_amdgcn_mfma_f32_16x16x32_f16(a0, b1, acc01, 0, 0, 0);
        acc10 = __builtin_amdgcn_mfma_f32_16x16x32_f16(a1, b0, acc10, 0, 0, 0);
        acc11 = __builtin_amdgcn_mfma_f32_16x16x32_f16(a1, b1, acc11, 0, 0, 0);
    }
    size_t rowBase = (size_t)(b * NN + m0 + og * 4) * TOTPOS;
    #pragma unroll
    for (int rr = 0; rr < 4; ++rr) {
        size_t ro0 = rowBase + (size_t)rr * TOTPOS;
        size_t ro1 = ro0 + (size_t)16 * TOTPOS;
        cws[ro0 + p0 + r]      = acc00[rr];
        cws[ro0 + p0 + 16 + r] = acc01[rr];
        cws[ro1 + p0 + r]      = acc10[rr];
        cws[ro1 + p0 + 16 + r] = acc11[rr];
    }
}

// -------------------- K4: upsample + MFMA conv1 + relu + conv2 + residual --------------------
// (unchanged from R3 — proven)
__global__ __launch_bounds__(256, 2) void k_fuse(const float* __restrict__ cws,
                                                 const float* __restrict__ w1,
                                                 const float* __restrict__ w2,
                                                 float* __restrict__ out) {
    __shared__ _Float16 cT[12 * 132 * 4];      // 12672 B
    __shared__ __half   hm[16 * 10 * 132];     // 42240 B
    __shared__ float    w2s[144];
    int img   = blockIdx.y;
    int strip = blockIdx.x;
    int y0 = strip * 8;
    int tid = threadIdx.x;
    int lane = tid & 63, wv = tid >> 6;
    int oc = lane & 15, og = lane >> 4;
    const float* cb = cws + (size_t)img * TOTPOS;

    if (tid < 144) w2s[tid] = w2[tid];

    f16x8 bf;
    #pragma unroll
    for (int e = 0; e < 8; ++e) {
        int k = og * 8 + e;
        bf[e] = (_Float16)w1[oc * 36 + (k & 3) * 9 + (k >> 2)];
    }
    h2 w22a, w22b;
    w22a[0] = (_Float16)w1[oc * 36 + 0 * 9 + 8];
    w22a[1] = (_Float16)w1[oc * 36 + 1 * 9 + 8];
    w22b[0] = (_Float16)w1[oc * 36 + 2 * 9 + 8];
    w22b[1] = (_Float16)w1[oc * 36 + 3 * 9 + 8];
    int ofs0, ofs1;
    {
        int kk0 = 2 * og,     ky0 = kk0 / 3, kx0 = kk0 - ky0 * 3;
        int kk1 = 2 * og + 1, ky1 = kk1 / 3, kx1 = kk1 - ky1 * 3;
        ofs0 = (ky0 * 132 + kx0 + 1 + oc) * 4;
        ofs1 = (ky1 * 132 + kx1 + 1 + oc) * 4;
    }
    {
        uint4 z; z.x = z.y = z.z = z.w = 0u;
        uint4* hp = (uint4*)hm;
        for (int i = tid; i < (16 * 10 * 132 * 2) / 16; i += 256) hp[i] = z;
    }
    for (int i = tid; i < 12 * 132; i += 256) {
        int ry = i / 132, rx = i - ry * 132;
        int gy = y0 + ry - 2, gx = rx - 2;
        f16x4 vv = {(_Float16)0.f, (_Float16)0.f, (_Float16)0.f, (_Float16)0.f};
        if ((unsigned)gy < HH && (unsigned)gx < WW) {
            vv[0] = (_Float16)cb[gy * WW + gx];
            #pragma unroll
            for (int l = 1; l < 4; ++l) {
                int hl = HH >> l, wl = WW >> l;
                int lvlOff = (l == 1) ? 12288 : (l == 2) ? 15360 : 16128;
                float invk = (l == 1) ? 0.5f : (l == 2) ? 0.25f : 0.125f;
                float fy = (gy + 0.5f) * invk - 0.5f;
                float fx = (gx + 0.5f) * invk - 0.5f;
                float y0f = floorf(fy), x0f = floorf(fx);
                float ty = fy - y0f, tx = fx - x0f;
                int iy = (int)y0f, ix = (int)x0f;
                int y1 = min(iy + 1, hl - 1);
                iy = min(max(iy, 0), hl - 1);
                int x1 = min(ix + 1, wl - 1);
                ix = min(max(ix, 0), wl - 1);
                const float* base = cb + lvlOff;
                float v00 = base[iy * wl + ix], v01 = base[iy * wl + x1];
                float v10 = base[y1 * wl + ix], v11 = base[y1 * wl + x1];
                float v = (1.f - ty) * ((1.f - tx) * v00 + tx * v01)
                        +        ty  * ((1.f - tx) * v10 + tx * v11);
                vv[l] = (_Float16)v;
            }
        }
        *(f16x4*)&cT[i * 4] = vv;
    }
    __syncthreads();

    for (int t = wv * 20; t < wv * 20 + 20; ++t) {
        int hy = t >> 3, xg = t & 7;
        if ((unsigned)(y0 + hy - 1) >= (unsigned)HH) continue;
        int base = hy * 528 + xg * 64;
        f16x4 a0 = *(const f16x4*)&cT[base + ofs0];
        f16x4 a1 = *(const f16x4*)&cT[base + ofs1];
        f16x8 A;
        #pragma unroll
        for (int e = 0; e < 4; ++e) { A[e] = a0[e]; A[4 + e] = a1[e]; }
        f32x4 acc = {0.f, 0.f, 0.f, 0.f};
        acc = __builtin_amdgcn_mfma_f32_16x16x32_f16(A, bf, acc, 0, 0, 0);
        int xb = xg * 16 + og * 4;
        #pragma unroll
        for (int r = 0; r < 4; ++r) {
            int x = xb + r;
            f16x4 cv = *(const f16x4*)&cT[(hy + 2) * 528 + (x + 3) * 4];
            h2 lo, hi;
            lo[0] = cv[0]; lo[1] = cv[1];
            hi[0] = cv[2]; hi[1] = cv[3];
            float v = acc[r];
            v = FDOT2(lo, w22a, v);
            v = FDOT2(hi, w22b, v);
            hm[oc * 1320 + hy * 132 + (x + 1)] = __float2half(fmaxf(v, 0.f));
        }
    }
    __syncthreads();

    int oy = tid >> 5, x4 = (tid & 31) * 4;
    float a2[4] = {0.f, 0.f, 0.f, 0.f};
    for (int ic = 0; ic < 16; ++ic) {
        float h[3][6];
        #pragma unroll
        for (int r = 0; r < 3; ++r)
            #pragma unroll
            for (int p = 0; p < 3; ++p) {
                __half2 t = *(const __half2*)&hm[ic * 1320 + (oy + r) * 132 + x4 + p * 2];
                float2 f2 = __half22float2(t);
                h[r][p*2] = f2.x; h[r][p*2+1] = f2.y;
            }
        #pragma unroll
        for (int ky = 0; ky < 3; ++ky)
            #pragma unroll
            for (int kx = 0; kx < 3; ++kx) {
                float w = w2s[ic * 9 + ky * 3 + kx];
                #pragma unroll
                for (int q = 0; q < 4; ++q)
                    a2[q] = fmaf(w, h[ky][q + kx], a2[q]);
            }
    }
    int gy = y0 + oy;
    const float4 res = *(const float4*)&cb[gy * WW + x4];
    float4 o;
    o.x = a2[0] + res.x; o.y = a2[1] + res.y;
    o.z = a2[2] + res.z; o.w = a2[3] + res.w;
    *(float4*)&out[(size_t)img * P0 + gy * WW + x4] = o;
}

extern "C" void kernel_launch(void* const* d_in, const int* in_sizes, int n_in,
                              void* d_out, int out_size, void* d_ws, size_t ws_size,
                              hipStream_t stream) {
    const float* q  = (const float*)d_in[0];
    const float* f  = (const float*)d_in[1];
    const float* w1 = (const float*)d_in[2];
    const float* w2 = (const float*)d_in[3];
    float* out = (float*)d_out;

    float* cws = (float*)d_ws;                                   // B*N*TOTPOS fp32
    _Float16* flnT = (_Float16*)(cws + (size_t)BB * NN * TOTPOS); // B*TOTPOS*C f16
    _Float16* qn16 = flnT + (size_t)BB * TOTPOS * CC;             // B*N*C f16

    hipLaunchKernelGGL(k_qnorm, dim3(BB * NN / 4), dim3(256), 0, stream, q, qn16);
    hipLaunchKernelGGL(k_pool_norm, dim3(TOTPOS, BB), dim3(256), 0, stream, f, flnT);
    hipLaunchKernelGGL(k_gemm, dim3(255, 4, BB), dim3(256), 0, stream, qn16, flnT, cws);
    hipLaunchKernelGGL(k_fuse, dim3(12, BB * NN), dim3(256), 0, stream, cws, w1, w2, out);
}